// Round 1
// baseline (1100.965 us; speedup 1.0000x reference)
//
#include <hip/hip_runtime.h>
#include <math.h>

#define NU_F 0.0031830988618379067f

// ----------------------------------------------------------------------------
// Equation kernel: 16 points/block, 4 channels (val, d/dt, d/dx, d2/dx2)
// -> M = 64 rows, N = K = 128. Fused across all 5 layers, state in LDS.
// Row layout: m = c*16 + p  (c = channel, p = local point)
// LDS H is K-major: Hs[feature][m] so A-reads are float4 along m.
// ----------------------------------------------------------------------------
__launch_bounds__(256, 2)
__global__ void eq_kernel(const float* __restrict__ tx,
                          const float* __restrict__ W0, const float* __restrict__ b0,
                          const float* __restrict__ W1, const float* __restrict__ b1,
                          const float* __restrict__ W2, const float* __restrict__ b2,
                          const float* __restrict__ W3, const float* __restrict__ b3,
                          const float* __restrict__ W4, const float* __restrict__ b4,
                          float* __restrict__ out)
{
    __shared__ float Hs[2][128][64];   // ping-pong state, 64 KB
    __shared__ float Ws[16 * 128];     // W chunk, 8 KB
    __shared__ float red[64];
    __shared__ float txs[32];

    const int tid = threadIdx.x;
    const int blk = blockIdx.x;
    const int tm  = tid >> 4;          // row group 0..15 (rows tm*4 .. tm*4+3)
    const int tn  = tid & 15;          // col group: cols {tn*4+j, 64+tn*4+j}
    const int tm4 = tm * 4;
    const int tn4 = tn * 4;

    if (tid < 32) txs[tid] = tx[blk * 32 + tid];
    __syncthreads();

    // ---- input layer (K=2, done pointwise) ----
    {
        const int p  = tid & 15;
        const int f0 = (tid >> 4) * 8;
        const float tv = txs[p * 2 + 0];
        const float xv = txs[p * 2 + 1];
        #pragma unroll
        for (int j = 0; j < 8; ++j) {
            const int f = f0 + j;
            const float w0 = W0[f];          // dz/dt
            const float w1 = W0[128 + f];    // dz/dx
            const float z  = fmaf(tv, w0, fmaf(xv, w1, b0[f]));
            const float a  = tanhf(z);
            const float s  = 1.f - a * a;
            Hs[0][f][p]      = a;
            Hs[0][f][16 + p] = s * w0;
            Hs[0][f][32 + p] = s * w1;
            Hs[0][f][48 + p] = -2.f * a * s * w1 * w1;  // a''*zx^2, zxx=0
        }
    }

    const float* Wl_arr[3] = {W1, W2, W3};
    const float* bl_arr[3] = {b1, b2, b3};
    int cur = 0;

    for (int layer = 0; layer < 3; ++layer) {
        const float* __restrict__ Wl = Wl_arr[layer];
        const float* __restrict__ bl = bl_arr[layer];
        float (* __restrict__ Hin)[64]  = Hs[cur];
        float (* __restrict__ Hout)[64] = Hs[cur ^ 1];

        float acc[4][8];
        #pragma unroll
        for (int i = 0; i < 4; ++i)
            #pragma unroll
            for (int j = 0; j < 8; ++j) acc[i][j] = 0.f;

        for (int ch = 0; ch < 8; ++ch) {
            __syncthreads();
            // stage 16 K-rows of W: 2048 floats, 2 float4 per thread, coalesced
            const float4* src = (const float4*)(Wl + ch * 16 * 128);
            float4* dst = (float4*)Ws;
            dst[tid]       = src[tid];
            dst[tid + 256] = src[tid + 256];
            __syncthreads();
            #pragma unroll
            for (int kk = 0; kk < 16; ++kk) {
                const int k = ch * 16 + kk;
                const float4 av  = *(const float4*)&Hin[k][tm4];
                const float4 bv0 = *(const float4*)&Ws[kk * 128 + tn4];
                const float4 bv1 = *(const float4*)&Ws[kk * 128 + 64 + tn4];
                const float ar[4] = {av.x, av.y, av.z, av.w};
                const float br[8] = {bv0.x, bv0.y, bv0.z, bv0.w,
                                     bv1.x, bv1.y, bv1.z, bv1.w};
                #pragma unroll
                for (int i = 0; i < 4; ++i)
                    #pragma unroll
                    for (int j = 0; j < 8; ++j)
                        acc[i][j] = fmaf(ar[i], br[j], acc[i][j]);
            }
        }

        // write raw Z (pre-activation) to Hout, vectorized along m
        #pragma unroll
        for (int j = 0; j < 8; ++j) {
            const int n = (j < 4) ? (tn4 + j) : (64 + tn4 + (j - 4));
            float4 v = make_float4(acc[0][j], acc[1][j], acc[2][j], acc[3][j]);
            *(float4*)&Hout[n][tm4] = v;
        }
        __syncthreads();

        // pointwise nonlinearity coupling the 4 channels of each (f, p)
        {
            const int f  = tid >> 1;
            const int p0 = (tid & 1) * 8;
            const float bias = bl[f];
            #pragma unroll
            for (int pi = 0; pi < 8; ++pi) {
                const int p = p0 + pi;
                const float z   = Hout[f][p];
                const float zt  = Hout[f][16 + p];
                const float zx  = Hout[f][32 + p];
                const float zxx = Hout[f][48 + p];
                const float a = tanhf(z + bias);
                const float s = 1.f - a * a;
                Hout[f][p]      = a;
                Hout[f][16 + p] = s * zt;
                Hout[f][32 + p] = s * zx;
                Hout[f][48 + p] = fmaf(s, zxx, -2.f * a * s * zx * zx);
            }
        }
        __syncthreads();
        cur ^= 1;
    }

    // ---- final layer (128 -> 1) + Burgers residual ----
    {
        float (* __restrict__ Hf)[64] = Hs[cur];
        const int m = tid >> 2;
        const int q = tid & 3;
        float partial = 0.f;
        #pragma unroll
        for (int i = 0; i < 32; ++i) {
            const int f = q * 32 + i;
            partial = fmaf(Hf[f][m], W4[f], partial);
        }
        partial += __shfl_down(partial, 2, 4);
        partial += __shfl_down(partial, 1, 4);
        if (q == 0) red[m] = partial;
    }
    __syncthreads();
    if (tid < 16) {
        const int p = tid;
        const float u   = red[p] + b4[0];
        const float ut  = red[16 + p];
        const float ux  = red[32 + p];
        const float uxx = red[48 + p];
        out[blk * 16 + p] = fmaf(u, ux, ut) - NU_F * uxx;
    }
}

// ----------------------------------------------------------------------------
// Init/boundary kernel: forward only. 64 points/block -> same M=64 GEMM shape.
// ----------------------------------------------------------------------------
__launch_bounds__(256, 2)
__global__ void ib_kernel(const float* __restrict__ tx_init,
                          const float* __restrict__ tx_bound,
                          const float* __restrict__ W0, const float* __restrict__ b0,
                          const float* __restrict__ W1, const float* __restrict__ b1,
                          const float* __restrict__ W2, const float* __restrict__ b2,
                          const float* __restrict__ W3, const float* __restrict__ b3,
                          const float* __restrict__ W4, const float* __restrict__ b4,
                          float* __restrict__ out)   // already offset to u_ib base
{
    __shared__ float Hs[2][128][64];
    __shared__ float Ws[16 * 128];
    __shared__ float txs[128];

    const int tid = threadIdx.x;
    const int blk = blockIdx.x;
    const int tm  = tid >> 4;
    const int tn  = tid & 15;
    const int tm4 = tm * 4;
    const int tn4 = tn * 4;

    if (tid < 128) {
        const int pl   = tid >> 1;
        const int comp = tid & 1;
        const int gp   = blk * 64 + pl;
        const float* src = (gp < 4096) ? tx_init : tx_bound;
        const int idx    = (gp < 4096) ? gp : (gp - 4096);
        txs[tid] = src[idx * 2 + comp];
    }
    __syncthreads();

    // input layer
    {
        const int p  = tid & 63;
        const int f0 = (tid >> 6) * 32;
        const float tv = txs[p * 2];
        const float xv = txs[p * 2 + 1];
        for (int j = 0; j < 32; ++j) {
            const int f = f0 + j;
            const float z = fmaf(tv, W0[f], fmaf(xv, W0[128 + f], b0[f]));
            Hs[0][f][p] = tanhf(z);
        }
    }

    const float* Wl_arr[3] = {W1, W2, W3};
    const float* bl_arr[3] = {b1, b2, b3};
    int cur = 0;

    for (int layer = 0; layer < 3; ++layer) {
        const float* __restrict__ Wl = Wl_arr[layer];
        const float* __restrict__ bl = bl_arr[layer];
        float (* __restrict__ Hin)[64]  = Hs[cur];
        float (* __restrict__ Hout)[64] = Hs[cur ^ 1];

        float acc[4][8];
        #pragma unroll
        for (int i = 0; i < 4; ++i)
            #pragma unroll
            for (int j = 0; j < 8; ++j) acc[i][j] = 0.f;

        for (int ch = 0; ch < 8; ++ch) {
            __syncthreads();
            const float4* src = (const float4*)(Wl + ch * 16 * 128);
            float4* dst = (float4*)Ws;
            dst[tid]       = src[tid];
            dst[tid + 256] = src[tid + 256];
            __syncthreads();
            #pragma unroll
            for (int kk = 0; kk < 16; ++kk) {
                const int k = ch * 16 + kk;
                const float4 av  = *(const float4*)&Hin[k][tm4];
                const float4 bv0 = *(const float4*)&Ws[kk * 128 + tn4];
                const float4 bv1 = *(const float4*)&Ws[kk * 128 + 64 + tn4];
                const float ar[4] = {av.x, av.y, av.z, av.w};
                const float br[8] = {bv0.x, bv0.y, bv0.z, bv0.w,
                                     bv1.x, bv1.y, bv1.z, bv1.w};
                #pragma unroll
                for (int i = 0; i < 4; ++i)
                    #pragma unroll
                    for (int j = 0; j < 8; ++j)
                        acc[i][j] = fmaf(ar[i], br[j], acc[i][j]);
            }
        }

        #pragma unroll
        for (int j = 0; j < 8; ++j) {
            const int n = (j < 4) ? (tn4 + j) : (64 + tn4 + (j - 4));
            float4 v = make_float4(acc[0][j], acc[1][j], acc[2][j], acc[3][j]);
            *(float4*)&Hout[n][tm4] = v;
        }
        __syncthreads();

        {
            const int f  = tid >> 1;
            const int p0 = (tid & 1) * 32;
            const float bias = bl[f];
            for (int pi = 0; pi < 32; ++pi) {
                const int p = p0 + pi;
                Hout[f][p] = tanhf(Hout[f][p] + bias);
            }
        }
        __syncthreads();
        cur ^= 1;
    }

    {
        float (* __restrict__ Hf)[64] = Hs[cur];
        const int m = tid >> 2;
        const int q = tid & 3;
        float partial = 0.f;
        #pragma unroll
        for (int i = 0; i < 32; ++i) {
            const int f = q * 32 + i;
            partial = fmaf(Hf[f][m], W4[f], partial);
        }
        partial += __shfl_down(partial, 2, 4);
        partial += __shfl_down(partial, 1, 4);
        if (q == 0) out[blk * 64 + m] = partial + b4[0];
    }
}

extern "C" void kernel_launch(void* const* d_in, const int* in_sizes, int n_in,
                              void* d_out, int out_size, void* d_ws, size_t ws_size,
                              hipStream_t stream)
{
    const float* tx_eq   = (const float*)d_in[0];
    const float* tx_init = (const float*)d_in[1];
    const float* tx_bnd  = (const float*)d_in[2];
    const float* W0 = (const float*)d_in[3];
    const float* b0 = (const float*)d_in[4];
    const float* W1 = (const float*)d_in[5];
    const float* b1 = (const float*)d_in[6];
    const float* W2 = (const float*)d_in[7];
    const float* b2 = (const float*)d_in[8];
    const float* W3 = (const float*)d_in[9];
    const float* b3 = (const float*)d_in[10];
    const float* W4 = (const float*)d_in[11];
    const float* b4 = (const float*)d_in[12];
    float* out = (float*)d_out;

    // 131072 eq points / 16 per block
    hipLaunchKernelGGL(eq_kernel, dim3(131072 / 16), dim3(256), 0, stream,
                       tx_eq, W0, b0, W1, b1, W2, b2, W3, b3, W4, b4, out);
    // 8192 init+bound points / 64 per block; output after the 131072 eq outputs
    hipLaunchKernelGGL(ib_kernel, dim3(8192 / 64), dim3(256), 0, stream,
                       tx_init, tx_bnd, W0, b0, W1, b1, W2, b2, W3, b3, W4, b4,
                       out + 131072);
}

// Round 2
// 806.030 us; speedup vs baseline: 1.3659x; 1.3659x over previous
//
#include <hip/hip_runtime.h>
#include <math.h>

#define NU_F 0.0031830988618379067f
// Row r (feature) stores m-group g's float4 at slot (g ^ (r&15)) -> bank-spread
#define SLOT(g, r) (((g) ^ ((r) & 15)) << 2)

// One fused kernel. Blocks 0..8191: equation points (16 pts/block, 4 channels
// {u, u_t, u_x, u_xx} -> M=64 rows, m = p*4 + c). Blocks 8192..8319: init/bound
// forward-only (64 pts/block, m = point). N=K=128, fused across all 5 layers.
// H state lives in ONE 32 KB LDS buffer, updated in place; activation and the
// derivative chain rule are applied in registers (each thread's 4 acc rows are
// the 4 channels of a single point).
__launch_bounds__(256, 4)
__global__ void pinn_kernel(const float* __restrict__ tx_eq,
                            const float* __restrict__ tx_init,
                            const float* __restrict__ tx_bnd,
                            const float* __restrict__ W0, const float* __restrict__ b0,
                            const float* __restrict__ W1, const float* __restrict__ b1,
                            const float* __restrict__ W2, const float* __restrict__ b2,
                            const float* __restrict__ W3, const float* __restrict__ b3,
                            const float* __restrict__ W4, const float* __restrict__ b4,
                            float* __restrict__ out)
{
    __shared__ float H[128][64];    // 32 KB state, in-place across layers
    __shared__ float Ws[8 * 128];   // 4 KB W chunk (8 K-rows)
    __shared__ float bs[128];
    __shared__ float w4s[128];
    __shared__ float txs[128];

    const int tid = threadIdx.x;
    const int blk = blockIdx.x;
    const bool is_eq = (blk < 8192);
    const int tm  = tid >> 4;       // m-group 0..15 (4 rows = 4 channels of pt tm / 4 pts)
    const int tn  = tid & 15;       // cols {tn*4+j, 64+tn*4+j}
    const int tn4 = tn * 4;

    if (tid < 128) w4s[tid] = W4[tid];
    if (is_eq) {
        if (tid < 32) txs[tid] = tx_eq[blk * 32 + tid];
    } else {
        if (tid < 128) {
            const int pl = tid >> 1, comp = tid & 1;
            const int gp = (blk - 8192) * 64 + pl;
            const float* src = (gp < 4096) ? tx_init : tx_bnd;
            const int idx = (gp < 4096) ? gp : gp - 4096;
            txs[tid] = src[idx * 2 + comp];
        }
    }
    __syncthreads();

    // ---- input layer (K=2, pointwise) ----
    if (is_eq) {
        const int p  = tid & 15;
        const int f0 = (tid >> 4) * 8;
        const float tv = txs[p * 2];
        const float xv = txs[p * 2 + 1];
        #pragma unroll
        for (int j = 0; j < 8; ++j) {
            const int f = f0 + j;
            const float w0 = W0[f];          // dz/dt
            const float w1 = W0[128 + f];    // dz/dx
            const float z = fmaf(tv, w0, fmaf(xv, w1, b0[f]));
            const float a = tanhf(z);
            const float s = 1.f - a * a;
            *(float4*)&H[f][SLOT(p, f)] =
                make_float4(a, s * w0, s * w1, -2.f * a * s * w1 * w1);
        }
    } else {
        const int pg = tid & 15;             // 4-point group
        const int f0 = (tid >> 4) * 8;
        float tv[4], xv[4];
        #pragma unroll
        for (int i = 0; i < 4; ++i) {
            tv[i] = txs[(pg * 4 + i) * 2];
            xv[i] = txs[(pg * 4 + i) * 2 + 1];
        }
        #pragma unroll
        for (int j = 0; j < 8; ++j) {
            const int f = f0 + j;
            const float w0 = W0[f];
            const float w1 = W0[128 + f];
            const float bb = b0[f];
            float4 v;
            v.x = tanhf(fmaf(tv[0], w0, fmaf(xv[0], w1, bb)));
            v.y = tanhf(fmaf(tv[1], w0, fmaf(xv[1], w1, bb)));
            v.z = tanhf(fmaf(tv[2], w0, fmaf(xv[2], w1, bb)));
            v.w = tanhf(fmaf(tv[3], w0, fmaf(xv[3], w1, bb)));
            *(float4*)&H[f][SLOT(pg, f)] = v;
        }
    }

    const float* Wl_arr[3] = {W1, W2, W3};
    const float* bl_arr[3] = {b1, b2, b3};

    for (int layer = 0; layer < 3; ++layer) {
        const float4* __restrict__ wsrc = (const float4*)Wl_arr[layer];
        const float* __restrict__ bl = bl_arr[layer];

        float acc[4][8];
        #pragma unroll
        for (int i = 0; i < 4; ++i)
            #pragma unroll
            for (int j = 0; j < 8; ++j) acc[i][j] = 0.f;

        float4 wreg = wsrc[tid];             // prefetch chunk 0
        #pragma unroll 1
        for (int ch = 0; ch < 16; ++ch) {
            __syncthreads();                 // prev chunk consumed / H visible
            ((float4*)Ws)[tid] = wreg;
            if (ch == 0 && tid < 128) bs[tid] = bl[tid];
            if (ch < 15) wreg = wsrc[(ch + 1) * 256 + tid];  // prefetch next
            __syncthreads();
            #pragma unroll
            for (int kk = 0; kk < 8; ++kk) {
                const int k = ch * 8 + kk;
                const float4 av  = *(const float4*)&H[k][SLOT(tm, k)];   // broadcast
                const float4 bv0 = *(const float4*)&Ws[kk * 128 + tn4];
                const float4 bv1 = *(const float4*)&Ws[kk * 128 + 64 + tn4];
                const float ar[4] = {av.x, av.y, av.z, av.w};
                const float br[8] = {bv0.x, bv0.y, bv0.z, bv0.w,
                                     bv1.x, bv1.y, bv1.z, bv1.w};
                #pragma unroll
                for (int i = 0; i < 4; ++i)
                    #pragma unroll
                    for (int j = 0; j < 8; ++j)
                        acc[i][j] = fmaf(ar[i], br[j], acc[i][j]);
            }
        }
        __syncthreads();   // all A-reads of this layer done -> in-place write OK

        if (is_eq) {
            // register-level activation + chain rule, swizzled conflict-free write
            #pragma unroll
            for (int j = 0; j < 8; ++j) {
                const int n = (j < 4) ? (tn4 + j) : (64 + tn4 + (j - 4));
                const float z   = acc[0][j] + bs[n];
                const float zt  = acc[1][j];
                const float zx  = acc[2][j];
                const float zxx = acc[3][j];
                const float a = tanhf(z);
                const float s = 1.f - a * a;
                *(float4*)&H[n][SLOT(tm, n)] =
                    make_float4(a, s * zt, s * zx,
                                fmaf(s, zxx, -2.f * a * s * zx * zx));
            }
        } else {
            #pragma unroll
            for (int j = 0; j < 8; ++j) {
                const int n = (j < 4) ? (tn4 + j) : (64 + tn4 + (j - 4));
                const float bb = bs[n];
                float4 v;
                v.x = tanhf(acc[0][j] + bb);
                v.y = tanhf(acc[1][j] + bb);
                v.z = tanhf(acc[2][j] + bb);
                v.w = tanhf(acc[3][j] + bb);
                *(float4*)&H[n][SLOT(tm, n)] = v;
            }
        }
    }

    __syncthreads();

    // ---- final layer (128 -> 1) + outputs ----
    {
        const int pg = tid >> 4;    // point / point-group
        const int q  = tid & 15;
        float4 sum = make_float4(0.f, 0.f, 0.f, 0.f);
        #pragma unroll
        for (int j = 0; j < 8; ++j) {
            const int f = q * 8 + j;
            const float w = w4s[f];
            const float4 h = *(const float4*)&H[f][SLOT(pg, f)];
            sum.x = fmaf(h.x, w, sum.x);
            sum.y = fmaf(h.y, w, sum.y);
            sum.z = fmaf(h.z, w, sum.z);
            sum.w = fmaf(h.w, w, sum.w);
        }
        #pragma unroll
        for (int m = 1; m <= 8; m <<= 1) {   // reduce across q (stays in 16-lane group)
            sum.x += __shfl_xor(sum.x, m);
            sum.y += __shfl_xor(sum.y, m);
            sum.z += __shfl_xor(sum.z, m);
            sum.w += __shfl_xor(sum.w, m);
        }
        if (q == 0) {
            if (is_eq) {
                const float u = sum.x + b4[0];   // sum = {u, ut, ux, uxx}
                out[blk * 16 + pg] = fmaf(u, sum.z, sum.y) - NU_F * sum.w;
            } else {
                const float bb = b4[0];
                const int base = 131072 + (blk - 8192) * 64 + pg * 4;  // sum = 4 points' u
                out[base + 0] = sum.x + bb;
                out[base + 1] = sum.y + bb;
                out[base + 2] = sum.z + bb;
                out[base + 3] = sum.w + bb;
            }
        }
    }
}

extern "C" void kernel_launch(void* const* d_in, const int* in_sizes, int n_in,
                              void* d_out, int out_size, void* d_ws, size_t ws_size,
                              hipStream_t stream)
{
    const float* tx_eq   = (const float*)d_in[0];
    const float* tx_init = (const float*)d_in[1];
    const float* tx_bnd  = (const float*)d_in[2];
    const float* W0 = (const float*)d_in[3];
    const float* b0 = (const float*)d_in[4];
    const float* W1 = (const float*)d_in[5];
    const float* b1 = (const float*)d_in[6];
    const float* W2 = (const float*)d_in[7];
    const float* b2 = (const float*)d_in[8];
    const float* W3 = (const float*)d_in[9];
    const float* b3 = (const float*)d_in[10];
    const float* W4 = (const float*)d_in[11];
    const float* b4 = (const float*)d_in[12];
    float* out = (float*)d_out;

    // 8192 eq blocks (16 pts each) + 128 ib blocks (64 pts each), one dispatch
    hipLaunchKernelGGL(pinn_kernel, dim3(8320), dim3(256), 0, stream,
                       tx_eq, tx_init, tx_bnd,
                       W0, b0, W1, b1, W2, b2, W3, b3, W4, b4, out);
}

// Round 3
// 761.848 us; speedup vs baseline: 1.4451x; 1.0580x over previous
//
#include <hip/hip_runtime.h>
#include <math.h>

#define NU_F 0.0031830988618379067f
#define MP 132   // padded m-stride: 132 dwords -> row r starts at bank 4r mod 32

// tanh via hardware exp: ~5 instructions vs branchy ocml tanhf.
// inf/underflow safe: e=inf -> 1; e=0 -> -1.
__device__ __forceinline__ float fast_tanh(float x) {
    const float e = __expf(2.f * x);
    return 1.f - 2.f / (e + 1.f);
}

// Blocks 0..4095: equation points, 32 pts/block, 4 channels {u,u_t,u_x,u_xx}
//   -> M = 128 rows, m = p*4 + c. Chain rule done in registers.
// Blocks 4096..4159: init/bound forward-only, 128 pts/block, m = p.
// N = K = 128 per layer, fused across all 5 layers; H state in LDS (in-place).
// Thread tile: 4 rows (4tm..4tm+3) x 16 cols {32q + 4tn + jj}.
__launch_bounds__(256, 2)
__global__ void pinn_kernel(const float* __restrict__ tx_eq,
                            const float* __restrict__ tx_init,
                            const float* __restrict__ tx_bnd,
                            const float* __restrict__ W0, const float* __restrict__ b0,
                            const float* __restrict__ W1, const float* __restrict__ b1,
                            const float* __restrict__ W2, const float* __restrict__ b2,
                            const float* __restrict__ W3, const float* __restrict__ b3,
                            const float* __restrict__ W4, const float* __restrict__ b4,
                            float* __restrict__ out)
{
    __shared__ float H[128][MP];     // 67.6 KB state, in-place across layers
    __shared__ float Ws[16 * 128];   // 8 KB W chunk (16 K-rows)
    __shared__ float bs[128];
    __shared__ float w4s[128];
    __shared__ float txs[256];
    __shared__ float red[128];

    const int tid = threadIdx.x;
    const int blk = blockIdx.x;
    const bool is_eq = (blk < 4096);
    const int tm  = tid >> 3;        // 0..31 -> rows 4tm..4tm+3
    const int tn  = tid & 7;         // cols {32q + 4tn + jj}
    const int tm4 = tm * 4;
    const int tn4 = tn * 4;

    if (tid < 128) w4s[tid] = W4[tid];
    Ws[tid] = W0[tid];               // W0 is 2x128 = 256 floats
    if (tid < 128) bs[tid] = b0[tid];
    if (is_eq) {
        if (tid < 64) txs[tid] = tx_eq[blk * 64 + tid];
    } else {
        const int gp = (blk - 4096) * 128 + (tid >> 1);
        const float* src = (gp < 4096) ? tx_init : tx_bnd;
        const int idx = (gp < 4096) ? gp : gp - 4096;
        txs[tid] = src[idx * 2 + (tid & 1)];
    }
    __syncthreads();

    // ---- input layer (K=2, pointwise) ----
    if (is_eq) {
        const int p  = tid & 31;
        const int f0 = (tid >> 5) * 16;
        const float tv = txs[2 * p], xv = txs[2 * p + 1];
        #pragma unroll
        for (int j = 0; j < 16; ++j) {
            const int f = f0 + j;
            const float w0 = Ws[f];          // dz/dt
            const float w1 = Ws[128 + f];    // dz/dx
            const float z = fmaf(tv, w0, fmaf(xv, w1, bs[f]));
            const float a = fast_tanh(z);
            const float s = 1.f - a * a;
            *(float4*)&H[f][4 * p] =
                make_float4(a, s * w0, s * w1, -2.f * a * s * w1 * w1);
        }
    } else {
        const int p  = tid & 127;
        const int f0 = (tid >> 7) * 64;
        const float tv = txs[2 * p], xv = txs[2 * p + 1];
        for (int j = 0; j < 64; ++j) {
            const int f = f0 + j;
            const float z = fmaf(tv, Ws[f], fmaf(xv, Ws[128 + f], bs[f]));
            H[f][p] = fast_tanh(z);
        }
    }

    const float* Wl_arr[3] = {W1, W2, W3};
    const float* bl_arr[3] = {b1, b2, b3};

    for (int layer = 0; layer < 3; ++layer) {
        const float4* __restrict__ wsrc = (const float4*)Wl_arr[layer];
        const float* __restrict__ bl = bl_arr[layer];

        float acc[4][16];
        #pragma unroll
        for (int i = 0; i < 4; ++i)
            #pragma unroll
            for (int j = 0; j < 16; ++j) acc[i][j] = 0.f;

        float4 wA = wsrc[tid];               // prefetch chunk 0 (2048 floats)
        float4 wB = wsrc[256 + tid];
        #pragma unroll 1
        for (int ch = 0; ch < 8; ++ch) {
            __syncthreads();                 // prev chunk consumed / H visible
            ((float4*)Ws)[tid]       = wA;
            ((float4*)Ws)[tid + 256] = wB;
            if (ch == 0 && tid < 128) bs[tid] = bl[tid];
            if (ch < 7) {
                wA = wsrc[(ch + 1) * 512 + tid];
                wB = wsrc[(ch + 1) * 512 + 256 + tid];
            }
            __syncthreads();
            #pragma unroll 4
            for (int kk = 0; kk < 16; ++kk) {
                const int k = ch * 16 + kk;
                const float4 av  = *(const float4*)&H[k][tm4];        // 8-addr bcast
                const float4 bv0 = *(const float4*)&Ws[kk * 128 + tn4];
                const float4 bv1 = *(const float4*)&Ws[kk * 128 + 32 + tn4];
                const float4 bv2 = *(const float4*)&Ws[kk * 128 + 64 + tn4];
                const float4 bv3 = *(const float4*)&Ws[kk * 128 + 96 + tn4];
                const float ar[4] = {av.x, av.y, av.z, av.w};
                const float br[16] = {bv0.x, bv0.y, bv0.z, bv0.w,
                                      bv1.x, bv1.y, bv1.z, bv1.w,
                                      bv2.x, bv2.y, bv2.z, bv2.w,
                                      bv3.x, bv3.y, bv3.z, bv3.w};
                #pragma unroll
                for (int i = 0; i < 4; ++i)
                    #pragma unroll
                    for (int j = 0; j < 16; ++j)
                        acc[i][j] = fmaf(ar[i], br[j], acc[i][j]);
            }
        }
        __syncthreads();   // all A-reads done -> in-place H overwrite is safe

        if (is_eq) {
            // register-level activation + chain rule
            #pragma unroll
            for (int q = 0; q < 4; ++q)
                #pragma unroll
                for (int jj = 0; jj < 4; ++jj) {
                    const int n = 32 * q + tn4 + jj;
                    const int idx = q * 4 + jj;
                    const float z   = acc[0][idx] + bs[n];
                    const float zt  = acc[1][idx];
                    const float zx  = acc[2][idx];
                    const float zxx = acc[3][idx];
                    const float a = fast_tanh(z);
                    const float s = 1.f - a * a;
                    *(float4*)&H[n][tm4] =
                        make_float4(a, s * zt, s * zx,
                                    fmaf(s, zxx, -2.f * a * s * zx * zx));
                }
        } else {
            #pragma unroll
            for (int q = 0; q < 4; ++q)
                #pragma unroll
                for (int jj = 0; jj < 4; ++jj) {
                    const int n = 32 * q + tn4 + jj;
                    const int idx = q * 4 + jj;
                    const float bb = bs[n];
                    float4 v;
                    v.x = fast_tanh(acc[0][idx] + bb);
                    v.y = fast_tanh(acc[1][idx] + bb);
                    v.z = fast_tanh(acc[2][idx] + bb);
                    v.w = fast_tanh(acc[3][idx] + bb);
                    *(float4*)&H[n][tm4] = v;
                }
        }
    }
    __syncthreads();

    // ---- final layer (128 -> 1) ----
    {
        const int m = tid >> 1;
        const int q = tid & 1;
        float partial = 0.f;
        #pragma unroll 8
        for (int i = 0; i < 64; ++i) {
            const int f = q * 64 + i;
            partial = fmaf(H[f][m], w4s[f], partial);
        }
        partial += __shfl_xor(partial, 1);
        if (q == 0) red[m] = partial;
    }
    __syncthreads();

    if (is_eq) {
        if (tid < 32) {
            const float4 r = *(const float4*)&red[4 * tid];  // {u', ut, ux, uxx}
            const float u = r.x + b4[0];
            out[blk * 32 + tid] = fmaf(u, r.z, r.y) - NU_F * r.w;
        }
    } else {
        if (tid < 128) {
            out[131072 + (blk - 4096) * 128 + tid] = red[tid] + b4[0];
        }
    }
}

extern "C" void kernel_launch(void* const* d_in, const int* in_sizes, int n_in,
                              void* d_out, int out_size, void* d_ws, size_t ws_size,
                              hipStream_t stream)
{
    const float* tx_eq   = (const float*)d_in[0];
    const float* tx_init = (const float*)d_in[1];
    const float* tx_bnd  = (const float*)d_in[2];
    const float* W0 = (const float*)d_in[3];
    const float* b0 = (const float*)d_in[4];
    const float* W1 = (const float*)d_in[5];
    const float* b1 = (const float*)d_in[6];
    const float* W2 = (const float*)d_in[7];
    const float* b2 = (const float*)d_in[8];
    const float* W3 = (const float*)d_in[9];
    const float* b3 = (const float*)d_in[10];
    const float* W4 = (const float*)d_in[11];
    const float* b4 = (const float*)d_in[12];
    float* out = (float*)d_out;

    // 4096 eq blocks (32 pts each) + 64 ib blocks (128 pts each)
    hipLaunchKernelGGL(pinn_kernel, dim3(4160), dim3(256), 0, stream,
                       tx_eq, tx_init, tx_bnd,
                       W0, b0, W1, b1, W2, b2, W3, b3, W4, b4, out);
}

// Round 4
// 501.240 us; speedup vs baseline: 2.1965x; 1.5199x over previous
//
#include <hip/hip_runtime.h>
#include <math.h>

#define NU_F 0.0031830988618379067f

typedef __attribute__((ext_vector_type(8))) _Float16 half8;
typedef __attribute__((ext_vector_type(2))) _Float16 half2_t;
typedef __attribute__((ext_vector_type(4))) float f32x4;

// physical half-index of 8-half block kb in row m (16B-granular XOR swizzle)
#define KSW(m, kb) ((((kb) ^ ((m) & 15)) << 3))

__device__ __forceinline__ float fast_tanh(float x) {
    const float e = __expf(2.f * x);
    return 1.f - 2.f / (e + 1.f);
}

// ---------------------------------------------------------------------------
// Weight prep: W[l][k][n] fp32 -> Wt_hi[l][n][k], Wt_lo[l][n][k] fp16 in ws.
// hi = fp16(w), lo = fp16(w - hi): w = hi + lo + O(2^-24 w).
// ---------------------------------------------------------------------------
__global__ void prep_kernel(const float* __restrict__ W1,
                            const float* __restrict__ W2,
                            const float* __restrict__ W3,
                            _Float16* __restrict__ ws)
{
    const int g = blockIdx.x * 256 + threadIdx.x;   // 0..49151
    const int l = g >> 14;
    const int r = g & 16383;
    const int n = r & 127;           // fast index -> coalesced read of W[k][n]
    const int k = r >> 7;
    const float* W = (l == 0) ? W1 : (l == 1) ? W2 : W3;
    const float w = W[k * 128 + n];
    const _Float16 hi = (_Float16)w;
    const _Float16 lo = (_Float16)(w - (float)hi);
    ws[l * 16384 + n * 128 + k]         = hi;
    ws[49152 + l * 16384 + n * 128 + k] = lo;
}

// ---------------------------------------------------------------------------
// Blocks 0..4095: equation, 32 pts (M=128 rows, m = 4p + channel).
// Blocks 4096..4159: init/bound forward-only, 128 pts (m = p).
// Wave w owns rows 32w..32w+31 exclusively -> NO __syncthreads anywhere.
// Per layer: D[m][n] = sum_k H[m][k] W[k][n] via 3-term split-fp16 MFMA
// (16x16x32), B-frags streamed from L2 (same W for all blocks).
// ---------------------------------------------------------------------------
__launch_bounds__(256, 2)
__global__ void pinn_kernel(const float* __restrict__ tx_eq,
                            const float* __restrict__ tx_init,
                            const float* __restrict__ tx_bnd,
                            const float* __restrict__ W0, const float* __restrict__ b0,
                            const float* __restrict__ b1, const float* __restrict__ b2,
                            const float* __restrict__ b3,
                            const float* __restrict__ W4, const float* __restrict__ b4,
                            const _Float16* __restrict__ wt,
                            float* __restrict__ out)
{
    __shared__ _Float16 Hhi[128][128];   // 32 KB
    __shared__ _Float16 Hlo[128][128];   // 32 KB

    const int tid  = threadIdx.x;
    const int blk  = blockIdx.x;
    const bool is_eq = (blk < 4096);
    const int w    = tid >> 6;
    const int lane = tid & 63;
    const int ln   = lane & 15;
    const int quad = lane >> 4;

    // ---- input layer (K=2, pointwise, fp32) ----
    if (is_eq) {
        const int pl = lane & 7;
        const int p  = 8 * w + pl;                 // block point, rows 4p..4p+3
        const int f0 = (lane >> 3) * 16;
        const float tv = tx_eq[blk * 64 + 2 * p];
        const float xv = tx_eq[blk * 64 + 2 * p + 1];
        const int m0 = 4 * p;
        #pragma unroll
        for (int j = 0; j < 16; j += 2) {
            float vch[2][4];
            #pragma unroll
            for (int e = 0; e < 2; ++e) {
                const int f = f0 + j + e;
                const float w0v = W0[f];           // dz/dt
                const float w1v = W0[128 + f];     // dz/dx
                const float z = fmaf(tv, w0v, fmaf(xv, w1v, b0[f]));
                const float a = fast_tanh(z);
                const float s = 1.f - a * a;
                vch[e][0] = a;
                vch[e][1] = s * w0v;
                vch[e][2] = s * w1v;
                vch[e][3] = -2.f * a * s * w1v * w1v;
            }
            const int f = f0 + j;
            const int off = KSW(0, f >> 3) ^ 0;    // block index same for all m? no:
            (void)off;
            #pragma unroll
            for (int c = 0; c < 4; ++c) {
                const int m = m0 + c;
                const _Float16 h0 = (_Float16)vch[0][c];
                const _Float16 h1 = (_Float16)vch[1][c];
                const _Float16 l0 = (_Float16)(vch[0][c] - (float)h0);
                const _Float16 l1 = (_Float16)(vch[1][c] - (float)h1);
                const int idx = KSW(m, f >> 3) + (f & 7);
                *(half2_t*)&Hhi[m][idx] = (half2_t){h0, h1};
                *(half2_t*)&Hlo[m][idx] = (half2_t){l0, l1};
            }
        }
    } else {
        const int pl = lane & 31;
        const int pb = 32 * w + pl;                // block point == row m
        const int gp = (blk - 4096) * 128 + pb;
        const float* src = (gp < 4096) ? tx_init : tx_bnd;
        const int idx = (gp < 4096) ? gp : gp - 4096;
        const float tv = src[2 * idx];
        const float xv = src[2 * idx + 1];
        const int f0 = (lane >> 5) * 64;
        #pragma unroll 4
        for (int j = 0; j < 64; j += 2) {
            float v0, v1;
            {
                const int f = f0 + j;
                v0 = fast_tanh(fmaf(tv, W0[f], fmaf(xv, W0[128 + f], b0[f])));
                v1 = fast_tanh(fmaf(tv, W0[f + 1], fmaf(xv, W0[128 + f + 1], b0[f + 1])));
            }
            const _Float16 h0 = (_Float16)v0, h1 = (_Float16)v1;
            const _Float16 l0 = (_Float16)(v0 - (float)h0), l1 = (_Float16)(v1 - (float)h1);
            const int f = f0 + j;
            const int ix = KSW(pb, f >> 3) + (f & 7);
            *(half2_t*)&Hhi[pb][ix] = (half2_t){h0, h1};
            *(half2_t*)&Hlo[pb][ix] = (half2_t){l0, l1};
        }
    }

    const float* barr[3] = {b1, b2, b3};

    #pragma unroll 1
    for (int layer = 0; layer < 3; ++layer) {
        const _Float16* __restrict__ Whi = wt + layer * 16384;
        const _Float16* __restrict__ Wlo = wt + 49152 + layer * 16384;
        const float* __restrict__ bl = barr[layer];

        float bias_v[8];
        #pragma unroll
        for (int c = 0; c < 8; ++c) bias_v[c] = bl[c * 16 + ln];

        f32x4 acc[2][8];
        #pragma unroll
        for (int rt = 0; rt < 2; ++rt)
            #pragma unroll
            for (int c = 0; c < 8; ++c) acc[rt][c] = (f32x4){0.f, 0.f, 0.f, 0.f};

        #pragma unroll 1
        for (int kt = 0; kt < 4; ++kt) {
            const int k0 = kt * 32 + quad * 8;     // this lane's k window
            half8 bh[8], blo[8];
            #pragma unroll
            for (int c = 0; c < 8; ++c) {
                const int n = c * 16 + ln;
                bh[c]  = *(const half8*)(Whi + n * 128 + k0);
                blo[c] = *(const half8*)(Wlo + n * 128 + k0);
            }
            half8 ah[2], al[2];
            #pragma unroll
            for (int rt = 0; rt < 2; ++rt) {
                const int m = 32 * w + 16 * rt + ln;
                const int ix = KSW(m, (kt * 4 + quad));
                ah[rt] = *(const half8*)&Hhi[m][ix];
                al[rt] = *(const half8*)&Hlo[m][ix];
            }
            #pragma unroll
            for (int c = 0; c < 8; ++c)
                #pragma unroll
                for (int rt = 0; rt < 2; ++rt) {
                    acc[rt][c] = __builtin_amdgcn_mfma_f32_16x16x32_f16(al[rt], bh[c],  acc[rt][c], 0, 0, 0);
                    acc[rt][c] = __builtin_amdgcn_mfma_f32_16x16x32_f16(ah[rt], blo[c], acc[rt][c], 0, 0, 0);
                    acc[rt][c] = __builtin_amdgcn_mfma_f32_16x16x32_f16(ah[rt], bh[c],  acc[rt][c], 0, 0, 0);
                }
        }

        // epilogue: lane's 4 acc regs = the 4 channels of one point (eq) /
        // 4 points (ib). Activation + chain rule in registers, re-split to LDS.
        const int m0e = 32 * w + 4 * quad;
        #pragma unroll
        for (int rt = 0; rt < 2; ++rt)
            #pragma unroll
            for (int c = 0; c < 8; ++c) {
                const int n = c * 16 + ln;
                const f32x4 A = acc[rt][c];
                float h[4];
                if (is_eq) {
                    const float z = A[0] + bias_v[c];
                    const float a = fast_tanh(z);
                    const float s = 1.f - a * a;
                    h[0] = a;
                    h[1] = s * A[1];
                    h[2] = s * A[2];
                    h[3] = fmaf(s, A[3], -2.f * a * s * A[2] * A[2]);
                } else {
                    h[0] = fast_tanh(A[0] + bias_v[c]);
                    h[1] = fast_tanh(A[1] + bias_v[c]);
                    h[2] = fast_tanh(A[2] + bias_v[c]);
                    h[3] = fast_tanh(A[3] + bias_v[c]);
                }
                #pragma unroll
                for (int r = 0; r < 4; ++r) {
                    const int m = m0e + 16 * rt + r;
                    const _Float16 hi = (_Float16)h[r];
                    const int ix = KSW(m, n >> 3) + (n & 7);
                    Hhi[m][ix] = hi;
                    Hlo[m][ix] = (_Float16)(h[r] - (float)hi);
                }
            }
    }

    // ---- final layer (128 -> 1), per-wave rows only ----
    {
        const float b4v = b4[0];
        const int hf   = lane & 1;
        const int mrow = 32 * w + (lane >> 1);
        float dot = 0.f;
        #pragma unroll
        for (int i = 0; i < 8; ++i) {
            const int f = hf * 64 + i * 8;
            const int ix = KSW(mrow, f >> 3);
            const half8 hh = *(const half8*)&Hhi[mrow][ix];
            const half8 hl = *(const half8*)&Hlo[mrow][ix];
            const float4 wa = *(const float4*)&W4[f];
            const float4 wb = *(const float4*)&W4[f + 4];
            dot = fmaf((float)hh[0] + (float)hl[0], wa.x, dot);
            dot = fmaf((float)hh[1] + (float)hl[1], wa.y, dot);
            dot = fmaf((float)hh[2] + (float)hl[2], wa.z, dot);
            dot = fmaf((float)hh[3] + (float)hl[3], wa.w, dot);
            dot = fmaf((float)hh[4] + (float)hl[4], wb.x, dot);
            dot = fmaf((float)hh[5] + (float)hl[5], wb.y, dot);
            dot = fmaf((float)hh[6] + (float)hl[6], wb.z, dot);
            dot = fmaf((float)hh[7] + (float)hl[7], wb.w, dot);
        }
        dot += __shfl_xor(dot, 1);                 // full dot at both lanes of pair

        if (is_eq) {
            const int pl2 = lane & 7;              // local point within wave
            const float uu   = __shfl(dot, 8 * pl2 + 0) + b4v;
            const float utv  = __shfl(dot, 8 * pl2 + 2);
            const float uxv  = __shfl(dot, 8 * pl2 + 4);
            const float uxxv = __shfl(dot, 8 * pl2 + 6);
            if (lane < 8)
                out[blk * 32 + 8 * w + pl2] = fmaf(uu, uxv, utv) - NU_F * uxxv;
        } else {
            if (!(lane & 1))
                out[131072 + (blk - 4096) * 128 + mrow] = dot + b4v;
        }
    }
}

extern "C" void kernel_launch(void* const* d_in, const int* in_sizes, int n_in,
                              void* d_out, int out_size, void* d_ws, size_t ws_size,
                              hipStream_t stream)
{
    const float* tx_eq   = (const float*)d_in[0];
    const float* tx_init = (const float*)d_in[1];
    const float* tx_bnd  = (const float*)d_in[2];
    const float* W0 = (const float*)d_in[3];
    const float* b0 = (const float*)d_in[4];
    const float* W1 = (const float*)d_in[5];
    const float* b1 = (const float*)d_in[6];
    const float* W2 = (const float*)d_in[7];
    const float* b2 = (const float*)d_in[8];
    const float* W3 = (const float*)d_in[9];
    const float* b3 = (const float*)d_in[10];
    const float* W4 = (const float*)d_in[11];
    const float* b4 = (const float*)d_in[12];
    float* out = (float*)d_out;
    _Float16* wt = (_Float16*)d_ws;   // needs 196608 B

    hipLaunchKernelGGL(prep_kernel, dim3(192), dim3(256), 0, stream, W1, W2, W3, wt);
    hipLaunchKernelGGL(pinn_kernel, dim3(4160), dim3(256), 0, stream,
                       tx_eq, tx_init, tx_bnd, W0, b0, b1, b2, b3, W4, b4,
                       (const _Float16*)wt, out);
}

// Round 5
// 281.431 us; speedup vs baseline: 3.9120x; 1.7810x over previous
//
#include <hip/hip_runtime.h>
#include <math.h>

#define NU_F 0.0031830988618379067f
#define HS 136   // halves per H row (k-stride): 17*8 -> 16B-aligned, bank-spread

typedef __attribute__((ext_vector_type(8))) _Float16 half8;
typedef __attribute__((ext_vector_type(16))) float f32x16;

__device__ __forceinline__ float fast_tanh(float x) {
    const float e = __expf(2.f * x);
    return 1.f - 2.f / (e + 1.f);
}

// ---------------------------------------------------------------------------
// Weight prep: W[l][k][n] fp32 -> Wt_hi[l][n][k], Wt_lo[l][n][k] fp16 in ws.
// hi = fp16(w), lo = fp16(w - hi): w = hi + lo + O(2^-24 w).
// ---------------------------------------------------------------------------
__global__ void prep_kernel(const float* __restrict__ W1,
                            const float* __restrict__ W2,
                            const float* __restrict__ W3,
                            _Float16* __restrict__ ws)
{
    const int g = blockIdx.x * 256 + threadIdx.x;   // 0..49151
    const int l = g >> 14;
    const int r = g & 16383;
    const int n = r & 127;           // fast index -> coalesced read of W[k][n]
    const int k = r >> 7;
    const float* W = (l == 0) ? W1 : (l == 1) ? W2 : W3;
    const float w = W[k * 128 + n];
    const _Float16 hi = (_Float16)w;
    const _Float16 lo = (_Float16)(w - (float)hi);
    ws[l * 16384 + n * 128 + k]         = hi;
    ws[49152 + l * 16384 + n * 128 + k] = lo;
}

// ---------------------------------------------------------------------------
// Blocks 0..4095: equation, 32 pts (M=128 rows, m = 4p + channel).
// Blocks 4096..4159: init/bound forward-only, 128 pts (m = p).
// Wave w computes output columns n in [32w, 32w+32) for ALL 128 rows.
// Whole layer's B-fragments (hi+lo) preloaded into 64 VGPRs -> the K-loop is
// pure {ds_read_b128 x8 + mfma x12} per kt. 3-term split-fp16 = fp32 accuracy.
// ---------------------------------------------------------------------------
__launch_bounds__(256, 2)
__global__ void pinn_kernel(const float* __restrict__ tx_eq,
                            const float* __restrict__ tx_init,
                            const float* __restrict__ tx_bnd,
                            const float* __restrict__ W0, const float* __restrict__ b0,
                            const float* __restrict__ b1, const float* __restrict__ b2,
                            const float* __restrict__ b3,
                            const float* __restrict__ W4, const float* __restrict__ b4,
                            const _Float16* __restrict__ wt,
                            float* __restrict__ out)
{
    __shared__ _Float16 Hhi[128][HS];   // 34 KB
    __shared__ _Float16 Hlo[128][HS];   // 34 KB

    const int tid   = threadIdx.x;
    const int blk   = blockIdx.x;
    const bool is_eq = (blk < 4096);
    const int w     = tid >> 6;
    const int lane  = tid & 63;
    const int col   = lane & 31;
    const int khalf = lane >> 5;        // k-subgroup within a frag (0/1)
    const int ncol  = 32 * w + col;     // this lane's output column

    // ---- input layer (K=2, pointwise, fp32) ----
    if (is_eq) {
        const int p  = tid >> 3;                 // 0..31
        const int f0 = (tid & 7) * 16;
        const float tv = tx_eq[blk * 64 + 2 * p];
        const float xv = tx_eq[blk * 64 + 2 * p + 1];
        float vch[4][16];
        #pragma unroll
        for (int j = 0; j < 16; ++j) {
            const int f = f0 + j;
            const float w0v = W0[f];             // dz/dt
            const float w1v = W0[128 + f];       // dz/dx
            const float z = fmaf(tv, w0v, fmaf(xv, w1v, b0[f]));
            const float a = fast_tanh(z);
            const float s = 1.f - a * a;
            vch[0][j] = a;
            vch[1][j] = s * w0v;
            vch[2][j] = s * w1v;
            vch[3][j] = -2.f * a * s * w1v * w1v;
        }
        const int m0 = 4 * p;
        #pragma unroll
        for (int c = 0; c < 4; ++c)
            #pragma unroll
            for (int g = 0; g < 2; ++g) {
                half8 hh, hl;
                #pragma unroll
                for (int j = 0; j < 8; ++j) {
                    const float v = vch[c][8 * g + j];
                    const _Float16 hi = (_Float16)v;
                    hh[j] = hi;
                    hl[j] = (_Float16)(v - (float)hi);
                }
                *(half8*)&Hhi[m0 + c][f0 + 8 * g] = hh;
                *(half8*)&Hlo[m0 + c][f0 + 8 * g] = hl;
            }
    } else {
        const int p  = tid >> 1;                 // 0..127 == row m
        const int f0 = (tid & 1) * 64;
        const int gp = (blk - 4096) * 128 + p;
        const float* src = (gp < 4096) ? tx_init : tx_bnd;
        const int idx = (gp < 4096) ? gp : gp - 4096;
        const float tv = src[2 * idx];
        const float xv = src[2 * idx + 1];
        #pragma unroll
        for (int g = 0; g < 8; ++g) {
            half8 hh, hl;
            #pragma unroll
            for (int j = 0; j < 8; ++j) {
                const int f = f0 + 8 * g + j;
                const float v = fast_tanh(fmaf(tv, W0[f], fmaf(xv, W0[128 + f], b0[f])));
                const _Float16 hi = (_Float16)v;
                hh[j] = hi;
                hl[j] = (_Float16)(v - (float)hi);
            }
            *(half8*)&Hhi[p][f0 + 8 * g] = hh;
            *(half8*)&Hlo[p][f0 + 8 * g] = hl;
        }
    }
    __syncthreads();

    const float* barr[3] = {b1, b2, b3};

    #pragma unroll 1
    for (int layer = 0; layer < 3; ++layer) {
        const _Float16* __restrict__ Whi = wt + layer * 16384;
        const _Float16* __restrict__ Wlo = wt + 49152 + layer * 16384;
        const float bias = barr[layer][ncol];

        // preload the whole layer's B (this wave's 32 columns): 64 VGPRs
        half8 Bh[8], Bl[8];
        #pragma unroll
        for (int kt = 0; kt < 8; ++kt) {
            const int k0 = kt * 16 + khalf * 8;
            Bh[kt] = *(const half8*)(Whi + ncol * 128 + k0);
            Bl[kt] = *(const half8*)(Wlo + ncol * 128 + k0);
        }

        f32x16 acc[4];
        #pragma unroll
        for (int mt = 0; mt < 4; ++mt)
            #pragma unroll
            for (int e = 0; e < 16; ++e) acc[mt][e] = 0.f;

        #pragma unroll
        for (int kt = 0; kt < 8; ++kt) {
            const int k0 = kt * 16 + khalf * 8;
            #pragma unroll
            for (int mt = 0; mt < 4; ++mt) {
                const int m = mt * 32 + col;
                const half8 ah = *(const half8*)&Hhi[m][k0];
                const half8 al = *(const half8*)&Hlo[m][k0];
                acc[mt] = __builtin_amdgcn_mfma_f32_32x32x16_f16(al, Bh[kt], acc[mt], 0, 0, 0);
                acc[mt] = __builtin_amdgcn_mfma_f32_32x32x16_f16(ah, Bl[kt], acc[mt], 0, 0, 0);
                acc[mt] = __builtin_amdgcn_mfma_f32_32x32x16_f16(ah, Bh[kt], acc[mt], 0, 0, 0);
            }
        }
        __syncthreads();   // all reads of H done -> in-place overwrite safe

        // epilogue: reg group 4g..4g+3 = rows (8g + 4*khalf) + {0,1,2,3};
        // for eq rows are {u,ut,ux,uxx} of one point -> chain rule in regs.
        #pragma unroll
        for (int mt = 0; mt < 4; ++mt)
            #pragma unroll
            for (int g = 0; g < 4; ++g) {
                const int mrow0 = mt * 32 + 8 * g + 4 * khalf;
                const float A0 = acc[mt][4 * g + 0];
                const float A1 = acc[mt][4 * g + 1];
                const float A2 = acc[mt][4 * g + 2];
                const float A3 = acc[mt][4 * g + 3];
                float h[4];
                if (is_eq) {
                    const float a = fast_tanh(A0 + bias);
                    const float s = 1.f - a * a;
                    h[0] = a;
                    h[1] = s * A1;
                    h[2] = s * A2;
                    h[3] = fmaf(s, A3, -2.f * a * s * A2 * A2);
                } else {
                    h[0] = fast_tanh(A0 + bias);
                    h[1] = fast_tanh(A1 + bias);
                    h[2] = fast_tanh(A2 + bias);
                    h[3] = fast_tanh(A3 + bias);
                }
                #pragma unroll
                for (int c = 0; c < 4; ++c) {
                    const _Float16 hi = (_Float16)h[c];
                    Hhi[mrow0 + c][ncol] = hi;
                    Hlo[mrow0 + c][ncol] = (_Float16)(h[c] - (float)hi);
                }
            }
        __syncthreads();
    }

    // ---- final layer (128 -> 1): wave w reduces rows 32w..32w+31 ----
    {
        const float b4v = b4[0];
        const int hf   = lane & 1;
        const int mrow = 32 * w + (lane >> 1);
        float dot = 0.f;
        #pragma unroll
        for (int i = 0; i < 8; ++i) {
            const int f = hf * 64 + i * 8;
            const half8 hh = *(const half8*)&Hhi[mrow][f];
            const half8 hl = *(const half8*)&Hlo[mrow][f];
            const float4 wa = *(const float4*)&W4[f];
            const float4 wb = *(const float4*)&W4[f + 4];
            dot = fmaf((float)hh[0] + (float)hl[0], wa.x, dot);
            dot = fmaf((float)hh[1] + (float)hl[1], wa.y, dot);
            dot = fmaf((float)hh[2] + (float)hl[2], wa.z, dot);
            dot = fmaf((float)hh[3] + (float)hl[3], wa.w, dot);
            dot = fmaf((float)hh[4] + (float)hl[4], wb.x, dot);
            dot = fmaf((float)hh[5] + (float)hl[5], wb.y, dot);
            dot = fmaf((float)hh[6] + (float)hl[6], wb.z, dot);
            dot = fmaf((float)hh[7] + (float)hl[7], wb.w, dot);
        }
        dot += __shfl_xor(dot, 1);      // full dot at both lanes of the pair

        if (is_eq) {
            const int pl2 = lane & 7;   // local point within wave
            const float uu   = __shfl(dot, 8 * pl2 + 0) + b4v;
            const float utv  = __shfl(dot, 8 * pl2 + 2);
            const float uxv  = __shfl(dot, 8 * pl2 + 4);
            const float uxxv = __shfl(dot, 8 * pl2 + 6);
            if (lane < 8)
                out[blk * 32 + 8 * w + pl2] = fmaf(uu, uxv, utv) - NU_F * uxxv;
        } else {
            if (!(lane & 1))
                out[131072 + (blk - 4096) * 128 + mrow] = dot + b4v;
        }
    }
}

extern "C" void kernel_launch(void* const* d_in, const int* in_sizes, int n_in,
                              void* d_out, int out_size, void* d_ws, size_t ws_size,
                              hipStream_t stream)
{
    const float* tx_eq   = (const float*)d_in[0];
    const float* tx_init = (const float*)d_in[1];
    const float* tx_bnd  = (const float*)d_in[2];
    const float* W0 = (const float*)d_in[3];
    const float* b0 = (const float*)d_in[4];
    const float* W1 = (const float*)d_in[5];
    const float* b1 = (const float*)d_in[6];
    const float* W2 = (const float*)d_in[7];
    const float* b2 = (const float*)d_in[8];
    const float* W3 = (const float*)d_in[9];
    const float* b3 = (const float*)d_in[10];
    const float* W4 = (const float*)d_in[11];
    const float* b4 = (const float*)d_in[12];
    float* out = (float*)d_out;
    _Float16* wt = (_Float16*)d_ws;   // needs 196608 B

    hipLaunchKernelGGL(prep_kernel, dim3(192), dim3(256), 0, stream, W1, W2, W3, wt);
    hipLaunchKernelGGL(pinn_kernel, dim3(4160), dim3(256), 0, stream,
                       tx_eq, tx_init, tx_bnd, W0, b0, b1, b2, b3, W4, b4,
                       (const _Float16*)wt, out);
}

// Round 6
// 273.197 us; speedup vs baseline: 4.0299x; 1.0301x over previous
//
#include <hip/hip_runtime.h>
#include <math.h>

#define NU_F 0.0031830988618379067f
#define HS 136   // halves per H row: 17*8 -> 16B-aligned, odd 16B-stride = bank-balanced

typedef __attribute__((ext_vector_type(8))) _Float16 half8;
typedef __attribute__((ext_vector_type(16))) float f32x16;

__device__ __forceinline__ float fast_tanh(float x) {
    const float e = __expf(2.f * x);
    return 1.f - 2.f / (e + 1.f);
}

// ---------------------------------------------------------------------------
// Weight prep: W[l][k][n] fp32 -> k-tiled fp16 hi/lo:
//   idx = l*16384 + (k>>4)*2048 + n*16 + (k&15)
// so a wave's per-kt B-read (n-contiguous, 16 halves each) is one 1KB block.
// ---------------------------------------------------------------------------
__global__ void prep_kernel(const float* __restrict__ W1,
                            const float* __restrict__ W2,
                            const float* __restrict__ W3,
                            _Float16* __restrict__ ws)
{
    const int g = blockIdx.x * 256 + threadIdx.x;   // 0..49151
    const int l = g >> 14;
    const int r = g & 16383;
    const int n = r & 127;           // fast index -> coalesced read of W[k][n]
    const int k = r >> 7;
    const float* W = (l == 0) ? W1 : (l == 1) ? W2 : W3;
    const float w = W[k * 128 + n];
    const _Float16 hi = (_Float16)w;
    const _Float16 lo = (_Float16)(w - (float)hi);
    const int idx = l * 16384 + (k >> 4) * 2048 + n * 16 + (k & 15);
    ws[idx]         = hi;
    ws[49152 + idx] = lo;
}

// ---------------------------------------------------------------------------
// Blocks 0..8191: equation, 16 pts (M=64 rows, m = 4p + channel).
// Blocks 8192..8319: init/bound forward-only, 64 pts (m = p).
// Wave w computes cols [32w,32w+32) for all 64 rows (mt=0,1).
// B streamed from L2 with distance-2 register prefetch; 3-term split-fp16
// MFMA (32x32x16) = fp32-grade accuracy; chain rule in registers via the
// C-layout property (reg&3 = channel).
// ---------------------------------------------------------------------------
__launch_bounds__(256, 4)
__global__ void pinn_kernel(const float* __restrict__ tx_eq,
                            const float* __restrict__ tx_init,
                            const float* __restrict__ tx_bnd,
                            const float* __restrict__ W0, const float* __restrict__ b0,
                            const float* __restrict__ b1, const float* __restrict__ b2,
                            const float* __restrict__ b3,
                            const float* __restrict__ W4, const float* __restrict__ b4,
                            const _Float16* __restrict__ wt,
                            float* __restrict__ out)
{
    __shared__ _Float16 Hhi[64][HS];   // 17.4 KB
    __shared__ _Float16 Hlo[64][HS];   // 17.4 KB

    const int tid   = threadIdx.x;
    const int blk   = blockIdx.x;
    const bool is_eq = (blk < 8192);
    const int w     = tid >> 6;
    const int lane  = tid & 63;
    const int col   = lane & 31;
    const int khalf = lane >> 5;
    const int ncol  = 32 * w + col;

    // ---- input layer (K=2, pointwise, fp32) ----
    if (is_eq) {
        const int p  = tid >> 4;                 // 0..15
        const int f0 = (tid & 15) * 8;
        const float tv = tx_eq[blk * 32 + 2 * p];
        const float xv = tx_eq[blk * 32 + 2 * p + 1];
        float vch[4][8];
        #pragma unroll
        for (int j = 0; j < 8; ++j) {
            const int f = f0 + j;
            const float w0v = W0[f];             // dz/dt
            const float w1v = W0[128 + f];       // dz/dx
            const float z = fmaf(tv, w0v, fmaf(xv, w1v, b0[f]));
            const float a = fast_tanh(z);
            const float s = 1.f - a * a;
            vch[0][j] = a;
            vch[1][j] = s * w0v;
            vch[2][j] = s * w1v;
            vch[3][j] = -2.f * a * s * w1v * w1v;
        }
        const int m0 = 4 * p;
        #pragma unroll
        for (int c = 0; c < 4; ++c) {
            half8 hh, hl;
            #pragma unroll
            for (int j = 0; j < 8; ++j) {
                const float v = vch[c][j];
                const _Float16 hi = (_Float16)v;
                hh[j] = hi;
                hl[j] = (_Float16)(v - (float)hi);
            }
            *(half8*)&Hhi[m0 + c][f0] = hh;
            *(half8*)&Hlo[m0 + c][f0] = hl;
        }
    } else {
        const int p  = tid >> 2;                 // 0..63 == row m
        const int f0 = (tid & 3) * 32;
        const int gp = (blk - 8192) * 64 + p;
        const float* src = (gp < 4096) ? tx_init : tx_bnd;
        const int idx = (gp < 4096) ? gp : gp - 4096;
        const float tv = src[2 * idx];
        const float xv = src[2 * idx + 1];
        #pragma unroll
        for (int g = 0; g < 4; ++g) {
            half8 hh, hl;
            #pragma unroll
            for (int j = 0; j < 8; ++j) {
                const int f = f0 + 8 * g + j;
                const float v = fast_tanh(fmaf(tv, W0[f], fmaf(xv, W0[128 + f], b0[f])));
                const _Float16 hi = (_Float16)v;
                hh[j] = hi;
                hl[j] = (_Float16)(v - (float)hi);
            }
            *(half8*)&Hhi[p][f0 + 8 * g] = hh;
            *(half8*)&Hlo[p][f0 + 8 * g] = hl;
        }
    }
    __syncthreads();

    const float* barr[3] = {b1, b2, b3};

    #pragma unroll 1
    for (int layer = 0; layer < 3; ++layer) {
        const _Float16* __restrict__ ph = wt + layer * 16384 + ncol * 16 + khalf * 8;
        const _Float16* __restrict__ pl = ph + 49152;
        const float bias = barr[layer][ncol];

        f32x16 acc[2];
        #pragma unroll
        for (int mt = 0; mt < 2; ++mt)
            #pragma unroll
            for (int e = 0; e < 16; ++e) acc[mt][e] = 0.f;

        // rolling distance-2 B prefetch (each load = coalesced 1KB/wave)
        half8 bh[2], bl[2];
        bh[0] = *(const half8*)(ph);         bl[0] = *(const half8*)(pl);
        bh[1] = *(const half8*)(ph + 2048);  bl[1] = *(const half8*)(pl + 2048);

        #pragma unroll
        for (int kt = 0; kt < 8; ++kt) {
            half8 nbh, nbl;
            if (kt < 6) {
                nbh = *(const half8*)(ph + (kt + 2) * 2048);
                nbl = *(const half8*)(pl + (kt + 2) * 2048);
            }
            const int k0 = kt * 16 + khalf * 8;
            #pragma unroll
            for (int mt = 0; mt < 2; ++mt) {
                const int m = mt * 32 + col;
                const half8 ah = *(const half8*)&Hhi[m][k0];
                const half8 al = *(const half8*)&Hlo[m][k0];
                acc[mt] = __builtin_amdgcn_mfma_f32_32x32x16_f16(al, bh[kt & 1], acc[mt], 0, 0, 0);
                acc[mt] = __builtin_amdgcn_mfma_f32_32x32x16_f16(ah, bl[kt & 1], acc[mt], 0, 0, 0);
                acc[mt] = __builtin_amdgcn_mfma_f32_32x32x16_f16(ah, bh[kt & 1], acc[mt], 0, 0, 0);
            }
            if (kt < 6) { bh[kt & 1] = nbh; bl[kt & 1] = nbl; }
        }
        __syncthreads();   // all reads of H done -> in-place overwrite safe

        // epilogue: reg group 4g..4g+3 = rows mt*32 + 8g + 4*khalf + {0..3};
        // eq: rows = {u,ut,ux,uxx} of one point -> chain rule in registers.
        #pragma unroll
        for (int mt = 0; mt < 2; ++mt)
            #pragma unroll
            for (int g = 0; g < 4; ++g) {
                const int mrow0 = mt * 32 + 8 * g + 4 * khalf;
                const float A0 = acc[mt][4 * g + 0];
                const float A1 = acc[mt][4 * g + 1];
                const float A2 = acc[mt][4 * g + 2];
                const float A3 = acc[mt][4 * g + 3];
                float h[4];
                if (is_eq) {
                    const float a = fast_tanh(A0 + bias);
                    const float s = 1.f - a * a;
                    h[0] = a;
                    h[1] = s * A1;
                    h[2] = s * A2;
                    h[3] = fmaf(s, A3, -2.f * a * s * A2 * A2);
                } else {
                    h[0] = fast_tanh(A0 + bias);
                    h[1] = fast_tanh(A1 + bias);
                    h[2] = fast_tanh(A2 + bias);
                    h[3] = fast_tanh(A3 + bias);
                }
                #pragma unroll
                for (int c = 0; c < 4; ++c) {
                    const _Float16 hi = (_Float16)h[c];
                    Hhi[mrow0 + c][ncol] = hi;
                    Hlo[mrow0 + c][ncol] = (_Float16)(h[c] - (float)hi);
                }
            }
        __syncthreads();
    }

    // ---- final layer (128 -> 1): thread t reduces k-quarter (t&3) of row t>>2
    {
        const float b4v = b4[0];
        const int m = tid >> 2;
        const int q = tid & 3;
        const int kb = 32 * q;
        float dot = 0.f;
        #pragma unroll
        for (int g = 0; g < 4; ++g) {
            const int f = kb + 8 * g;
            const half8 hh = *(const half8*)&Hhi[m][f];
            const half8 hl = *(const half8*)&Hlo[m][f];
            const float4 wa = *(const float4*)&W4[f];
            const float4 wb = *(const float4*)&W4[f + 4];
            dot = fmaf((float)hh[0] + (float)hl[0], wa.x, dot);
            dot = fmaf((float)hh[1] + (float)hl[1], wa.y, dot);
            dot = fmaf((float)hh[2] + (float)hl[2], wa.z, dot);
            dot = fmaf((float)hh[3] + (float)hl[3], wa.w, dot);
            dot = fmaf((float)hh[4] + (float)hl[4], wb.x, dot);
            dot = fmaf((float)hh[5] + (float)hl[5], wb.y, dot);
            dot = fmaf((float)hh[6] + (float)hl[6], wb.z, dot);
            dot = fmaf((float)hh[7] + (float)hl[7], wb.w, dot);
        }
        dot += __shfl_xor(dot, 1);   // reduce across the 4 k-quarters
        dot += __shfl_xor(dot, 2);   // full row-dot at all 4 lanes of the row

        if (is_eq) {
            // wave w holds rows [16w,16w+16) = points [4w,4w+4); lane = 16p' + 4c + q
            const float uu   = __shfl(dot, (lane & 48) + 0)  + b4v;
            const float utv  = __shfl(dot, (lane & 48) + 4);
            const float uxv  = __shfl(dot, (lane & 48) + 8);
            const float uxxv = __shfl(dot, (lane & 48) + 12);
            if ((lane & 15) == 0)
                out[blk * 16 + 4 * w + (lane >> 4)] = fmaf(uu, uxv, utv) - NU_F * uxxv;
        } else {
            if (q == 0)
                out[131072 + (blk - 8192) * 64 + m] = dot + b4v;
        }
    }
}

extern "C" void kernel_launch(void* const* d_in, const int* in_sizes, int n_in,
                              void* d_out, int out_size, void* d_ws, size_t ws_size,
                              hipStream_t stream)
{
    const float* tx_eq   = (const float*)d_in[0];
    const float* tx_init = (const float*)d_in[1];
    const float* tx_bnd  = (const float*)d_in[2];
    const float* W0 = (const float*)d_in[3];
    const float* b0 = (const float*)d_in[4];
    const float* W1 = (const float*)d_in[5];
    const float* b1 = (const float*)d_in[6];
    const float* W2 = (const float*)d_in[7];
    const float* b2 = (const float*)d_in[8];
    const float* W3 = (const float*)d_in[9];
    const float* b3 = (const float*)d_in[10];
    const float* W4 = (const float*)d_in[11];
    const float* b4 = (const float*)d_in[12];
    float* out = (float*)d_out;
    _Float16* wt = (_Float16*)d_ws;   // needs 196608 B

    hipLaunchKernelGGL(prep_kernel, dim3(192), dim3(256), 0, stream, W1, W2, W3, wt);
    // 8192 eq blocks (16 pts) + 128 ib blocks (64 pts)
    hipLaunchKernelGGL(pinn_kernel, dim3(8320), dim3(256), 0, stream,
                       tx_eq, tx_init, tx_bnd, W0, b0, b1, b2, b3, W4, b4,
                       (const _Float16*)wt, out);
}